// Round 3
// baseline (880.227 us; speedup 1.0000x reference)
//
#include <hip/hip_runtime.h>
#include <math.h>

// ---------------------------------------------------------------------------
// GCN dual-branch, algebraically restructured:
//   ax = A'x  (128 feats)            [A' = D^-1/2 (A+I) D^-1/2]
//   branch1: y16 = relu(ax@W1 + b1) @ (W2@Wc); cls = A'(y16) + (b2@Wc+bc)
//   branch2 (fully linear): g1 = ax@Me + c1 ; g_{k+1} = A'(g_k) + c_{k+1}
//            trust = sigmoid(A'(g3) + be4@Wt + bt)
// edge_index is INT32 (JAX x64 disabled).
// ---------------------------------------------------------------------------

#define SM_W2C   0        // 256*16
#define SM_T4    4096     // 128*2
#define SM_T3    4352
#define SM_T2    4608
#define SM_ME    4864
#define SM_CLSC  5120     // 16
#define SM_C1    5136     // 2
#define SM_C2    5138
#define SM_C3    5140
#define SM_FC    5142     // 2  (be4@Wt + bt)
#define SM_TOTAL 5248

__global__ __launch_bounds__(256) void k_deg(const int* __restrict__ ei,
                                             int* __restrict__ deg, int E, int N) {
  int e = blockIdx.x * 256 + threadIdx.x;
  if (e < E) {
    unsigned c = (unsigned)ei[E + e];
    if (c >= (unsigned)N) c = 0;
    atomicAdd(&deg[c], 1);
  }
}

__global__ __launch_bounds__(256) void k_dis(const int* __restrict__ deg,
                                             float* __restrict__ dis, int N) {
  int i = blockIdx.x * 256 + threadIdx.x;
  if (i < N) dis[i] = 1.0f / sqrtf((float)deg[i] + 1.0f);
}

__global__ __launch_bounds__(1024) void k_scan(const int* __restrict__ cnt,
                                               int* __restrict__ rowptr, int n) {
  __shared__ int wsum[16];
  __shared__ int s_carry;
  int tid = threadIdx.x, lane = tid & 63, wid = tid >> 6;
  if (tid == 0) { s_carry = 0; rowptr[0] = 0; }
  __syncthreads();
  for (int base = 0; base < n; base += 1024) {
    int i = base + tid;
    int v = (i < n) ? cnt[i] : 0;
    int x = v;
    #pragma unroll
    for (int off = 1; off < 64; off <<= 1) {
      int t = __shfl_up(x, off, 64);
      if (lane >= off) x += t;
    }
    if (lane == 63) wsum[wid] = x;
    __syncthreads();
    if (wid == 0 && lane < 16) {
      int ws = wsum[lane];
      #pragma unroll
      for (int off = 1; off < 16; off <<= 1) {
        int t = __shfl_up(ws, off, 64);
        if (lane >= off) ws += t;
      }
      wsum[lane] = ws;
    }
    __syncthreads();
    int incl = x + (wid ? wsum[wid - 1] : 0);
    int carry = s_carry;
    if (i < n) rowptr[i + 1] = carry + incl;
    __syncthreads();
    if (tid == 1023) s_carry = carry + incl;
    __syncthreads();
  }
}

__global__ __launch_bounds__(256) void k_scatter(const int* __restrict__ ei,
                                                 const int* __restrict__ rowptr,
                                                 int* __restrict__ cnt,
                                                 const float* __restrict__ dis,
                                                 int* __restrict__ csr_src,
                                                 float* __restrict__ csr_w,
                                                 int E, int N) {
  int e = blockIdx.x * 256 + threadIdx.x;
  if (e >= E) return;
  unsigned r = (unsigned)ei[e];
  unsigned c = (unsigned)ei[E + e];
  if (r >= (unsigned)N) r = 0;
  if (c >= (unsigned)N) c = 0;
  int pos = rowptr[c] + atomicAdd(&cnt[c], 1);
  csr_src[pos] = (int)r;
  csr_w[pos] = dis[r] * dis[c];
}

__global__ __launch_bounds__(256) void k_precompute(
    const float* __restrict__ W2, const float* __restrict__ b2,
    const float* __restrict__ Wc, const float* __restrict__ bc,
    const float* __restrict__ We1, const float* __restrict__ be1,
    const float* __restrict__ We2, const float* __restrict__ be2,
    const float* __restrict__ We3, const float* __restrict__ be3,
    const float* __restrict__ We4, const float* __restrict__ be4,
    const float* __restrict__ Wt, const float* __restrict__ bt,
    float* __restrict__ sm) {
  int tid = threadIdx.x;
  {
    int r = tid >> 1, c = tid & 1; float s = 0.f;
    for (int k = 0; k < 128; ++k) s += We4[r * 128 + k] * Wt[k * 2 + c];
    sm[SM_T4 + r * 2 + c] = s;
  }
  __syncthreads();
  {
    int r = tid >> 1, c = tid & 1; float s = 0.f;
    for (int k = 0; k < 128; ++k) s += We3[r * 128 + k] * sm[SM_T4 + k * 2 + c];
    sm[SM_T3 + r * 2 + c] = s;
  }
  __syncthreads();
  {
    int r = tid >> 1, c = tid & 1; float s = 0.f;
    for (int k = 0; k < 128; ++k) s += We2[r * 128 + k] * sm[SM_T3 + k * 2 + c];
    sm[SM_T2 + r * 2 + c] = s;
  }
  __syncthreads();
  {
    int r = tid >> 1, c = tid & 1; float s = 0.f;
    for (int k = 0; k < 128; ++k) s += We1[r * 128 + k] * sm[SM_T2 + k * 2 + c];
    sm[SM_ME + r * 2 + c] = s;
  }
  for (int o = tid; o < 4096; o += 256) {
    int r = o >> 4, c = o & 15; float s = 0.f;
    for (int k = 0; k < 128; ++k) s += W2[r * 128 + k] * Wc[k * 16 + c];
    sm[SM_W2C + o] = s;
  }
  if (tid < 16) {
    float s = 0.f;
    for (int k = 0; k < 128; ++k) s += b2[k] * Wc[k * 16 + tid];
    sm[SM_CLSC + tid] = s + bc[tid];
  }
  __syncthreads();
  if (tid < 2) {
    float s = 0.f;
    for (int k = 0; k < 128; ++k) s += be1[k] * sm[SM_T2 + k * 2 + tid];
    sm[SM_C1 + tid] = s;
    s = 0.f;
    for (int k = 0; k < 128; ++k) s += be2[k] * sm[SM_T3 + k * 2 + tid];
    sm[SM_C2 + tid] = s;
    s = 0.f;
    for (int k = 0; k < 128; ++k) s += be3[k] * sm[SM_T4 + k * 2 + tid];
    sm[SM_C3 + tid] = s;
    s = 0.f;
    for (int k = 0; k < 128; ++k) s += be4[k] * Wt[k * 2 + tid];
    sm[SM_FC + tid] = s + bt[tid];
  }
}

// ax = A'x (wave per node) + fused g1 = ax@Me + c1.
// csr indices/weights loaded coalesced per 64-edge chunk, distributed via readlane.
__global__ __launch_bounds__(256) void k_agg128(
    const float* __restrict__ x, const int* __restrict__ rowptr,
    const int* __restrict__ csr_src, const float* __restrict__ csr_w,
    const float* __restrict__ dis, const float* __restrict__ sm,
    float* __restrict__ ax, float* __restrict__ ga, int N) {
  int node = blockIdx.x * 4 + (threadIdx.x >> 6);
  if (node >= N) return;
  int lane = threadIdx.x & 63;
  const float2* x2 = (const float2*)x;
  float d = dis[node];
  float2 v = x2[(size_t)node * 64 + lane];
  float a0 = d * d * v.x, a1 = d * d * v.y;
  int e = rowptr[node], end = rowptr[node + 1];
  while (e < end) {
    int rem = end - e;
    int cnt = rem < 64 ? rem : 64;
    int off = lane < cnt ? lane : cnt - 1;
    int src_l = csr_src[e + off];
    int w_l = __float_as_int(csr_w[e + off]);
    for (int i = 0; i < cnt; ++i) {
      int s = __builtin_amdgcn_readlane(src_l, i);
      float w = __int_as_float(__builtin_amdgcn_readlane(w_l, i));
      float2 u = x2[(size_t)s * 64 + lane];
      a0 = fmaf(w, u.x, a0);
      a1 = fmaf(w, u.y, a1);
    }
    e += 64;
  }
  ((float2*)ax)[(size_t)node * 64 + lane] = make_float2(a0, a1);
  float4 me = *(const float4*)&sm[SM_ME + lane * 4];
  float p0 = a0 * me.x + a1 * me.z;
  float p1 = a0 * me.y + a1 * me.w;
  #pragma unroll
  for (int m = 32; m; m >>= 1) { p0 += __shfl_xor(p0, m); p1 += __shfl_xor(p1, m); }
  if (lane == 0)
    ((float2*)ga)[node] = make_float2(p0 + sm[SM_C1 + 0], p1 + sm[SM_C1 + 1]);
}

// y16 = relu(ax @ W1 + b1) @ W2c, fused.
// BM=64 (full-K A-tile in LDS, staged once), four 64-col passes, TM=2, TN=8.
// tx = tid&7 (8 lanes -> 64 cols), ty = tid>>3 (32 -> 64 rows).
__global__ __launch_bounds__(256, 3) void k_gemm_fused(
    const float* __restrict__ A, const float* __restrict__ W1,
    const float* __restrict__ b1, const float* __restrict__ sm,
    float* __restrict__ Y, int N) {
  __shared__ float As[64][132];  // row-major, full K (33.8 KB)
  __shared__ float Bs[32][68];   // k x 64 cols (8.7 KB)
  int tid = threadIdx.x;
  int tx = tid & 7, ty = tid >> 3;
  int m0 = blockIdx.x * 64;
  // stage A-tile once: 2048 float4, 8 per thread (coalesced global reads)
  #pragma unroll
  for (int it = 0; it < 8; ++it) {
    int idx = it * 256 + tid;
    int row = idx >> 5, kc = idx & 31;
    int gr = m0 + row; gr = gr < N ? gr : N - 1;
    *(float4*)&As[row][kc * 4] = *(const float4*)&A[(size_t)gr * 128 + kc * 4];
  }
  float p[2][16];
  #pragma unroll
  for (int i = 0; i < 2; ++i)
    #pragma unroll
    for (int c = 0; c < 16; ++c) p[i][c] = 0.f;

  for (int n0 = 0; n0 < 256; n0 += 64) {
    float acc[2][8];
    #pragma unroll
    for (int i = 0; i < 2; ++i)
      #pragma unroll
      for (int j = 0; j < 8; ++j) acc[i][j] = 0.f;

    for (int k0 = 0; k0 < 128; k0 += 32) {
      __syncthreads();
      #pragma unroll
      for (int it = 0; it < 2; ++it) {
        int idx = it * 256 + tid;
        int kb = idx >> 4, c4 = (idx & 15) * 4;
        *(float4*)&Bs[kb][c4] = *(const float4*)&W1[(size_t)(k0 + kb) * 256 + n0 + c4];
      }
      __syncthreads();
      #pragma unroll
      for (int k = 0; k < 32; ++k) {
        float a0 = As[ty * 2][k0 + k];
        float a1 = As[ty * 2 + 1][k0 + k];
        float4 b0 = *(const float4*)&Bs[k][tx * 8];
        float4 b1v = *(const float4*)&Bs[k][tx * 8 + 4];
        float b[8] = {b0.x, b0.y, b0.z, b0.w, b1v.x, b1v.y, b1v.z, b1v.w};
        #pragma unroll
        for (int j = 0; j < 8; ++j) {
          acc[0][j] = fmaf(a0, b[j], acc[0][j]);
          acc[1][j] = fmaf(a1, b[j], acc[1][j]);
        }
      }
    }
    // fold: p[i][c] += relu(acc[i][j] + b1[n0+tx*8+j]) * W2c[n0+tx*8+j][c]
    float4 bb0 = *(const float4*)&b1[n0 + tx * 8];
    float4 bb1 = *(const float4*)&b1[n0 + tx * 8 + 4];
    float bb[8] = {bb0.x, bb0.y, bb0.z, bb0.w, bb1.x, bb1.y, bb1.z, bb1.w};
    #pragma unroll
    for (int j = 0; j < 8; ++j) {
      const float* wr = &sm[SM_W2C + (size_t)(n0 + tx * 8 + j) * 16];
      float4 w0 = *(const float4*)&wr[0];
      float4 w1 = *(const float4*)&wr[4];
      float4 w2 = *(const float4*)&wr[8];
      float4 w3 = *(const float4*)&wr[12];
      float wj[16] = {w0.x, w0.y, w0.z, w0.w, w1.x, w1.y, w1.z, w1.w,
                      w2.x, w2.y, w2.z, w2.w, w3.x, w3.y, w3.z, w3.w};
      float o0 = acc[0][j] + bb[j]; o0 = o0 > 0.f ? o0 : 0.f;
      float o1 = acc[1][j] + bb[j]; o1 = o1 > 0.f ? o1 : 0.f;
      #pragma unroll
      for (int c = 0; c < 16; ++c) {
        p[0][c] = fmaf(o0, wj[c], p[0][c]);
        p[1][c] = fmaf(o1, wj[c], p[1][c]);
      }
    }
  }
  // reduce p over the 8 tx lanes (lane bits 0..2)
  #pragma unroll
  for (int i = 0; i < 2; ++i)
    #pragma unroll
    for (int c = 0; c < 16; ++c) {
      float v = p[i][c];
      v += __shfl_xor(v, 1);
      v += __shfl_xor(v, 2);
      v += __shfl_xor(v, 4);
      p[i][c] = v;
    }
  if (tx == 0) {
    #pragma unroll
    for (int i = 0; i < 2; ++i) {
      int gr = m0 + ty * 2 + i;
      if (gr < N) {
        *(float4*)&Y[(size_t)gr * 16 + 0]  = make_float4(p[i][0], p[i][1], p[i][2], p[i][3]);
        *(float4*)&Y[(size_t)gr * 16 + 4]  = make_float4(p[i][4], p[i][5], p[i][6], p[i][7]);
        *(float4*)&Y[(size_t)gr * 16 + 8]  = make_float4(p[i][8], p[i][9], p[i][10], p[i][11]);
        *(float4*)&Y[(size_t)gr * 16 + 12] = make_float4(p[i][12], p[i][13], p[i][14], p[i][15]);
      }
    }
  }
}

// cls = A'(y16) + cls_const  (16 lanes per node) -> d_out
__global__ __launch_bounds__(256) void k_agg16(
    const float* __restrict__ Y, const int* __restrict__ rowptr,
    const int* __restrict__ csr_src, const float* __restrict__ csr_w,
    const float* __restrict__ dis, const float* __restrict__ sm,
    float* __restrict__ out, int N) {
  int node = blockIdx.x * 16 + (threadIdx.x >> 4);
  if (node >= N) return;
  int sl = threadIdx.x & 15;
  float d = dis[node];
  float acc = d * d * Y[(size_t)node * 16 + sl];
  int e = rowptr[node], end = rowptr[node + 1];
  for (; e < end; ++e) {
    int s = csr_src[e]; float w = csr_w[e];
    acc = fmaf(w, Y[(size_t)s * 16 + sl], acc);
  }
  out[(size_t)node * 16 + sl] = acc + sm[SM_CLSC + sl];
}

// g_out = A'(g_in) + cadd  (2 feats, thread per node); FINAL adds sigmoid
template <int FINAL>
__global__ __launch_bounds__(256) void k_agg2(
    const float* __restrict__ gin, const int* __restrict__ rowptr,
    const int* __restrict__ csr_src, const float* __restrict__ csr_w,
    const float* __restrict__ dis, const float* __restrict__ cadd,
    float* __restrict__ gout, int N) {
  int i = blockIdx.x * 256 + threadIdx.x;
  if (i >= N) return;
  const float2* g2 = (const float2*)gin;
  float d = dis[i];
  float2 v = g2[i];
  float a0 = d * d * v.x, a1 = d * d * v.y;
  int e = rowptr[i], end = rowptr[i + 1];
  for (; e < end; ++e) {
    int s = csr_src[e]; float w = csr_w[e];
    float2 u = g2[s];
    a0 = fmaf(w, u.x, a0); a1 = fmaf(w, u.y, a1);
  }
  a0 += cadd[0]; a1 += cadd[1];
  if (FINAL) {
    a0 = 1.f / (1.f + expf(-a0));
    a1 = 1.f / (1.f + expf(-a1));
  }
  ((float2*)gout)[i] = make_float2(a0, a1);
}

extern "C" void kernel_launch(void* const* d_in, const int* in_sizes, int n_in,
                              void* d_out, int out_size, void* d_ws, size_t ws_size,
                              hipStream_t stream) {
  const float* x = (const float*)d_in[0];
  const int* ei = (const int*)d_in[1];   // int32
  const float* W1 = (const float*)d_in[2];
  const float* b1 = (const float*)d_in[3];
  const float* W2 = (const float*)d_in[4];
  const float* b2 = (const float*)d_in[5];
  const float* Wc = (const float*)d_in[6];
  const float* bc = (const float*)d_in[7];
  const float* We1 = (const float*)d_in[8];
  const float* be1 = (const float*)d_in[9];
  const float* We2 = (const float*)d_in[10];
  const float* be2 = (const float*)d_in[11];
  const float* We3 = (const float*)d_in[12];
  const float* be3 = (const float*)d_in[13];
  const float* We4 = (const float*)d_in[14];
  const float* be4 = (const float*)d_in[15];
  const float* Wt = (const float*)d_in[16];
  const float* bt = (const float*)d_in[17];
  float* out = (float*)d_out;

  const int N = in_sizes[0] / 128;
  const int E = in_sizes[1] / 2;

  char* ws = (char*)d_ws;
  size_t off = 0;
  auto alloc = [&](size_t bytes) {
    size_t o = off;
    off = (off + bytes + 255) & ~(size_t)255;
    return o;
  };
  int* deg = (int*)(ws + alloc((size_t)N * 4));
  int* cnt = (int*)(ws + alloc((size_t)N * 4));
  int* rowptr = (int*)(ws + alloc(((size_t)N + 1) * 4));
  float* dis = (float*)(ws + alloc((size_t)N * 4));
  int* csr_src = (int*)(ws + alloc((size_t)E * 4));
  float* csr_w = (float*)(ws + alloc((size_t)E * 4));
  float* ax = (float*)(ws + alloc((size_t)N * 128 * 4));
  float* y16 = (float*)(ws + alloc((size_t)N * 16 * 4));
  float* ga = (float*)(ws + alloc((size_t)N * 2 * 4));
  float* gb = (float*)(ws + alloc((size_t)N * 2 * 4));
  float* sm = (float*)(ws + alloc((size_t)SM_TOTAL * 4));

  hipMemsetAsync(deg, 0, (size_t)N * 4, stream);
  hipMemsetAsync(cnt, 0, (size_t)N * 4, stream);

  k_precompute<<<1, 256, 0, stream>>>(W2, b2, Wc, bc, We1, be1, We2, be2, We3,
                                      be3, We4, be4, Wt, bt, sm);
  k_deg<<<(E + 255) / 256, 256, 0, stream>>>(ei, deg, E, N);
  k_dis<<<(N + 255) / 256, 256, 0, stream>>>(deg, dis, N);
  k_scan<<<1, 1024, 0, stream>>>(deg, rowptr, N);
  k_scatter<<<(E + 255) / 256, 256, 0, stream>>>(ei, rowptr, cnt, dis, csr_src,
                                                 csr_w, E, N);
  k_agg128<<<(N + 3) / 4, 256, 0, stream>>>(x, rowptr, csr_src, csr_w, dis, sm,
                                            ax, ga, N);
  k_gemm_fused<<<(N + 63) / 64, 256, 0, stream>>>(ax, W1, b1, sm, y16, N);
  k_agg16<<<(N + 15) / 16, 256, 0, stream>>>(y16, rowptr, csr_src, csr_w, dis,
                                             sm, out, N);
  k_agg2<0><<<(N + 255) / 256, 256, 0, stream>>>(ga, rowptr, csr_src, csr_w,
                                                 dis, sm + SM_C2, gb, N);
  k_agg2<0><<<(N + 255) / 256, 256, 0, stream>>>(gb, rowptr, csr_src, csr_w,
                                                 dis, sm + SM_C3, ga, N);
  k_agg2<1><<<(N + 255) / 256, 256, 0, stream>>>(
      ga, rowptr, csr_src, csr_w, dis, sm + SM_FC, out + (size_t)N * 16, N);
}

// Round 4
// 725.247 us; speedup vs baseline: 1.2137x; 1.2137x over previous
//
#include <hip/hip_runtime.h>
#include <math.h>

// ---------------------------------------------------------------------------
// GCN dual-branch, algebraically restructured:
//   ax = A'x  (128 feats)            [A' = D^-1/2 (A+I) D^-1/2]
//   branch1: y16 = relu(ax@W1 + b1) @ (W2@Wc); cls = A'(y16) + (b2@Wc+bc)
//   branch2 (fully linear): g1 = ax@Me + c1 ; g_{k+1} = A'(g_k) + c_{k+1}
//            trust = sigmoid(A'(g3) + be4@Wt + bt)
// edge_index is INT32 (JAX x64 disabled).
// GEMM runs on MFMA via split-bf16 (hi+lo), ~fp32 accuracy at bf16-MFMA rate.
// ---------------------------------------------------------------------------

#define SM_W2C   0        // 256*16
#define SM_T4    4096     // 128*2
#define SM_T3    4352
#define SM_T2    4608
#define SM_ME    4864
#define SM_CLSC  5120     // 16
#define SM_C1    5136     // 2
#define SM_C2    5138
#define SM_C3    5140
#define SM_FC    5142     // 2  (be4@Wt + bt)
#define SM_TOTAL 5248

typedef __attribute__((ext_vector_type(8))) short bf16x8;
typedef __attribute__((ext_vector_type(4))) float f32x4;
#define MFMA16(a, b, c) __builtin_amdgcn_mfma_f32_16x16x32_bf16(a, b, c, 0, 0, 0)

__device__ inline unsigned short f2bf(float f) {  // RNE f32 -> bf16 bits
  unsigned u = __float_as_uint(f);
  u += 0x7fffu + ((u >> 16) & 1u);
  return (unsigned short)(u >> 16);
}
__device__ inline float bf2f(unsigned short h) {
  return __uint_as_float((unsigned)h << 16);
}

__global__ __launch_bounds__(256) void k_deg(const int* __restrict__ ei,
                                             int* __restrict__ deg, int E, int N) {
  int e = blockIdx.x * 256 + threadIdx.x;
  if (e < E) {
    unsigned c = (unsigned)ei[E + e];
    if (c >= (unsigned)N) c = 0;
    atomicAdd(&deg[c], 1);
  }
}

__global__ __launch_bounds__(256) void k_dis(const int* __restrict__ deg,
                                             float* __restrict__ dis, int N) {
  int i = blockIdx.x * 256 + threadIdx.x;
  if (i < N) dis[i] = 1.0f / sqrtf((float)deg[i] + 1.0f);
}

__global__ __launch_bounds__(1024) void k_scan(const int* __restrict__ cnt,
                                               int* __restrict__ rowptr, int n) {
  __shared__ int wsum[16];
  __shared__ int s_carry;
  int tid = threadIdx.x, lane = tid & 63, wid = tid >> 6;
  if (tid == 0) { s_carry = 0; rowptr[0] = 0; }
  __syncthreads();
  for (int base = 0; base < n; base += 1024) {
    int i = base + tid;
    int v = (i < n) ? cnt[i] : 0;
    int x = v;
    #pragma unroll
    for (int off = 1; off < 64; off <<= 1) {
      int t = __shfl_up(x, off, 64);
      if (lane >= off) x += t;
    }
    if (lane == 63) wsum[wid] = x;
    __syncthreads();
    if (wid == 0 && lane < 16) {
      int ws = wsum[lane];
      #pragma unroll
      for (int off = 1; off < 16; off <<= 1) {
        int t = __shfl_up(ws, off, 64);
        if (lane >= off) ws += t;
      }
      wsum[lane] = ws;
    }
    __syncthreads();
    int incl = x + (wid ? wsum[wid - 1] : 0);
    int carry = s_carry;
    if (i < n) rowptr[i + 1] = carry + incl;
    __syncthreads();
    if (tid == 1023) s_carry = carry + incl;
    __syncthreads();
  }
}

__global__ __launch_bounds__(256) void k_scatter(const int* __restrict__ ei,
                                                 const int* __restrict__ rowptr,
                                                 int* __restrict__ cnt,
                                                 const float* __restrict__ dis,
                                                 int* __restrict__ csr_src,
                                                 float* __restrict__ csr_w,
                                                 int E, int N) {
  int e = blockIdx.x * 256 + threadIdx.x;
  if (e >= E) return;
  unsigned r = (unsigned)ei[e];
  unsigned c = (unsigned)ei[E + e];
  if (r >= (unsigned)N) r = 0;
  if (c >= (unsigned)N) c = 0;
  int pos = rowptr[c] + atomicAdd(&cnt[c], 1);
  csr_src[pos] = (int)r;
  csr_w[pos] = dis[r] * dis[c];
}

// fold weight chains + bf16 hi/lo splits of W1 and W2c
__global__ __launch_bounds__(256) void k_precompute(
    const float* __restrict__ W1,
    const float* __restrict__ W2, const float* __restrict__ b2,
    const float* __restrict__ Wc, const float* __restrict__ bc,
    const float* __restrict__ We1, const float* __restrict__ be1,
    const float* __restrict__ We2, const float* __restrict__ be2,
    const float* __restrict__ We3, const float* __restrict__ be3,
    const float* __restrict__ We4, const float* __restrict__ be4,
    const float* __restrict__ Wt, const float* __restrict__ bt,
    float* __restrict__ sm,
    unsigned short* __restrict__ w1h, unsigned short* __restrict__ w1l,
    unsigned short* __restrict__ w2h, unsigned short* __restrict__ w2l) {
  int tid = threadIdx.x;
  {
    int r = tid >> 1, c = tid & 1; float s = 0.f;
    for (int k = 0; k < 128; ++k) s += We4[r * 128 + k] * Wt[k * 2 + c];
    sm[SM_T4 + r * 2 + c] = s;
  }
  __syncthreads();
  {
    int r = tid >> 1, c = tid & 1; float s = 0.f;
    for (int k = 0; k < 128; ++k) s += We3[r * 128 + k] * sm[SM_T4 + k * 2 + c];
    sm[SM_T3 + r * 2 + c] = s;
  }
  __syncthreads();
  {
    int r = tid >> 1, c = tid & 1; float s = 0.f;
    for (int k = 0; k < 128; ++k) s += We2[r * 128 + k] * sm[SM_T3 + k * 2 + c];
    sm[SM_T2 + r * 2 + c] = s;
  }
  __syncthreads();
  {
    int r = tid >> 1, c = tid & 1; float s = 0.f;
    for (int k = 0; k < 128; ++k) s += We1[r * 128 + k] * sm[SM_T2 + k * 2 + c];
    sm[SM_ME + r * 2 + c] = s;
  }
  for (int o = tid; o < 4096; o += 256) {
    int r = o >> 4, c = o & 15; float s = 0.f;
    for (int k = 0; k < 128; ++k) s += W2[r * 128 + k] * Wc[k * 16 + c];
    sm[SM_W2C + o] = s;
  }
  if (tid < 16) {
    float s = 0.f;
    for (int k = 0; k < 128; ++k) s += b2[k] * Wc[k * 16 + tid];
    sm[SM_CLSC + tid] = s + bc[tid];
  }
  __syncthreads();
  if (tid < 2) {
    float s = 0.f;
    for (int k = 0; k < 128; ++k) s += be1[k] * sm[SM_T2 + k * 2 + tid];
    sm[SM_C1 + tid] = s;
    s = 0.f;
    for (int k = 0; k < 128; ++k) s += be2[k] * sm[SM_T3 + k * 2 + tid];
    sm[SM_C2 + tid] = s;
    s = 0.f;
    for (int k = 0; k < 128; ++k) s += be3[k] * sm[SM_T4 + k * 2 + tid];
    sm[SM_C3 + tid] = s;
    s = 0.f;
    for (int k = 0; k < 128; ++k) s += be4[k] * Wt[k * 2 + tid];
    sm[SM_FC + tid] = s + bt[tid];
  }
  // w1t[c][k] split of W1[k][c]  (k-contiguous per col -> 16B frag loads)
  for (int idx = tid; idx < 32768; idx += 256) {
    int c = idx >> 7, k = idx & 127;
    float v = W1[(size_t)k * 256 + c];
    unsigned short h = f2bf(v);
    w1h[idx] = h;
    w1l[idx] = f2bf(v - bf2f(h));
  }
  // w2t[c][k] split of W2c[k][c]
  for (int idx = tid; idx < 4096; idx += 256) {
    int c = idx >> 8, k = idx & 255;
    float v = sm[SM_W2C + k * 16 + c];
    unsigned short h = f2bf(v);
    w2h[idx] = h;
    w2l[idx] = f2bf(v - bf2f(h));
  }
}

// ax = A'x (wave per node), written as bf16 hi/lo split; fused g1 = ax@Me + c1
__global__ __launch_bounds__(256) void k_agg128(
    const float* __restrict__ x, const int* __restrict__ rowptr,
    const int* __restrict__ csr_src, const float* __restrict__ csr_w,
    const float* __restrict__ dis, const float* __restrict__ sm,
    unsigned short* __restrict__ axh, unsigned short* __restrict__ axl,
    float* __restrict__ ga, int N) {
  int node = blockIdx.x * 4 + (threadIdx.x >> 6);
  if (node >= N) return;
  int lane = threadIdx.x & 63;
  const float2* x2 = (const float2*)x;
  float d = dis[node];
  float2 v = x2[(size_t)node * 64 + lane];
  float a0 = d * d * v.x, a1 = d * d * v.y;
  int e = rowptr[node], end = rowptr[node + 1];
  while (e < end) {
    int rem = end - e;
    int cnt = rem < 64 ? rem : 64;
    int off = lane < cnt ? lane : cnt - 1;
    int src_l = csr_src[e + off];
    int w_l = __float_as_int(csr_w[e + off]);
    for (int i = 0; i < cnt; ++i) {
      int s = __builtin_amdgcn_readlane(src_l, i);
      float w = __int_as_float(__builtin_amdgcn_readlane(w_l, i));
      float2 u = x2[(size_t)s * 64 + lane];
      a0 = fmaf(w, u.x, a0);
      a1 = fmaf(w, u.y, a1);
    }
    e += 64;
  }
  unsigned short h0 = f2bf(a0), h1v = f2bf(a1);
  unsigned short l0 = f2bf(a0 - bf2f(h0)), l1 = f2bf(a1 - bf2f(h1v));
  ((unsigned int*)axh)[(size_t)node * 64 + lane] = (unsigned)h0 | ((unsigned)h1v << 16);
  ((unsigned int*)axl)[(size_t)node * 64 + lane] = (unsigned)l0 | ((unsigned)l1 << 16);
  float4 me = *(const float4*)&sm[SM_ME + lane * 4];
  float p0 = a0 * me.x + a1 * me.z;
  float p1 = a0 * me.y + a1 * me.w;
  #pragma unroll
  for (int m = 32; m; m >>= 1) { p0 += __shfl_xor(p0, m); p1 += __shfl_xor(p1, m); }
  if (lane == 0)
    ((float2*)ga)[node] = make_float2(p0 + sm[SM_C1 + 0], p1 + sm[SM_C1 + 1]);
}

// y16 = relu(ax@W1 + b1) @ W2c via split-bf16 MFMA.
// Block: 64 rows, 4 waves; wave w owns cols w*64..w*64+64 of h1.
// MFMA 16x16x32 layouts: A row=lane&15,k=(lane>>4)*8+j ; B col=lane&15,same k;
// C/D col=lane&15,row=(lane>>4)*4+reg (verified).
// LDS (64KB): phase1 A-tile hi/lo [64][128]; phase3/4 h1 hi/lo [64][256],
// both with chunk-XOR swizzle (col ^ ((row&7)<<3)) for bank-even b128 reads.
__global__ __launch_bounds__(256, 2) void k_gemm_mfma(
    const unsigned short* __restrict__ axh, const unsigned short* __restrict__ axl,
    const unsigned short* __restrict__ w1h, const unsigned short* __restrict__ w1l,
    const unsigned short* __restrict__ w2h, const unsigned short* __restrict__ w2l,
    const float* __restrict__ b1, float* __restrict__ Y, int N) {
  __shared__ unsigned short lds[32768];  // 64 KB
  int tid = threadIdx.x, lane = tid & 63, w = tid >> 6;
  int r16 = lane & 15, kh = lane >> 4;
  int m0 = blockIdx.x * 64;
  // phase 1: stage A tile (hi at lds[0..8191], lo at lds[8192..16383])
  #pragma unroll
  for (int it = 0; it < 8; ++it) {
    int idx = it * 256 + tid;            // 0..2047 chunks of 16B
    int arr = idx >> 10, rem = idx & 1023;
    int row = rem >> 4, ch = rem & 15;
    int gr = m0 + row; if (gr > N - 1) gr = N - 1;
    const unsigned short* src = (arr ? axl : axh) + (size_t)gr * 128 + ch * 8;
    uint4 vv = *(const uint4*)src;
    *(uint4*)&lds[arr * 8192 + row * 128 + ((ch ^ (row & 7)) * 8)] = vv;
  }
  __syncthreads();
  f32x4 acc[4][4];
  #pragma unroll
  for (int i = 0; i < 4; ++i)
    #pragma unroll
    for (int j = 0; j < 4; ++j) acc[i][j] = (f32x4){0.f, 0.f, 0.f, 0.f};
  #pragma unroll
  for (int ks = 0; ks < 4; ++ks) {
    bf16x8 bh[4], bl[4];
    #pragma unroll
    for (int nt = 0; nt < 4; ++nt) {
      int col = w * 64 + nt * 16 + r16;
      size_t boff = (size_t)col * 128 + ks * 32 + kh * 8;
      bh[nt] = *(const bf16x8*)(w1h + boff);
      bl[nt] = *(const bf16x8*)(w1l + boff);
    }
    #pragma unroll
    for (int mt = 0; mt < 4; ++mt) {
      int row = mt * 16 + r16;
      int ch = ks * 4 + kh;
      int off = row * 128 + ((ch ^ (row & 7)) * 8);
      bf16x8 ah = *(const bf16x8*)&lds[off];
      bf16x8 al = *(const bf16x8*)&lds[8192 + off];
      #pragma unroll
      for (int nt = 0; nt < 4; ++nt) {
        acc[mt][nt] = MFMA16(ah, bh[nt], acc[mt][nt]);
        acc[mt][nt] = MFMA16(ah, bl[nt], acc[mt][nt]);
        acc[mt][nt] = MFMA16(al, bh[nt], acc[mt][nt]);
      }
    }
  }
  __syncthreads();  // all A reads complete before overwriting LDS with h1
  // phase 3: bias + relu + hi/lo split -> lds as h1 [64][256] (swizzled)
  #pragma unroll
  for (int nt = 0; nt < 4; ++nt) {
    int colL = w * 64 + nt * 16 + r16;
    float bv = b1[colL];
    #pragma unroll
    for (int mt = 0; mt < 4; ++mt) {
      #pragma unroll
      for (int r = 0; r < 4; ++r) {
        int rowL = mt * 16 + kh * 4 + r;
        float vv = acc[mt][nt][r] + bv;
        vv = vv > 0.f ? vv : 0.f;
        unsigned short hh = f2bf(vv);
        unsigned short ll = f2bf(vv - bf2f(hh));
        int idx = rowL * 256 + (colL ^ ((rowL & 7) << 3));
        lds[idx] = hh;
        lds[16384 + idx] = ll;
      }
    }
  }
  __syncthreads();
  // phase 4: wave w computes y16 rows w*16..w*16+16 over K=256
  f32x4 y = (f32x4){0.f, 0.f, 0.f, 0.f};
  int rowL = w * 16 + r16;
  #pragma unroll
  for (int k2 = 0; k2 < 8; ++k2) {
    int cb = k2 * 32 + kh * 8;
    int idx = rowL * 256 + (cb ^ ((rowL & 7) << 3));
    bf16x8 a2h = *(const bf16x8*)&lds[idx];
    bf16x8 a2l = *(const bf16x8*)&lds[16384 + idx];
    size_t boff = (size_t)r16 * 256 + cb;
    bf16x8 b2h = *(const bf16x8*)(w2h + boff);
    bf16x8 b2l = *(const bf16x8*)(w2l + boff);
    y = MFMA16(a2h, b2h, y);
    y = MFMA16(a2h, b2l, y);
    y = MFMA16(a2l, b2h, y);
  }
  #pragma unroll
  for (int r = 0; r < 4; ++r) {
    int gr = m0 + w * 16 + kh * 4 + r;
    if (gr < N) Y[(size_t)gr * 16 + r16] = y[r];
  }
}

// cls = A'(y16) + cls_const  (16 lanes per node) -> d_out
__global__ __launch_bounds__(256) void k_agg16(
    const float* __restrict__ Y, const int* __restrict__ rowptr,
    const int* __restrict__ csr_src, const float* __restrict__ csr_w,
    const float* __restrict__ dis, const float* __restrict__ sm,
    float* __restrict__ out, int N) {
  int node = blockIdx.x * 16 + (threadIdx.x >> 4);
  if (node >= N) return;
  int sl = threadIdx.x & 15;
  float d = dis[node];
  float acc = d * d * Y[(size_t)node * 16 + sl];
  int e = rowptr[node], end = rowptr[node + 1];
  for (; e < end; ++e) {
    int s = csr_src[e]; float w = csr_w[e];
    acc = fmaf(w, Y[(size_t)s * 16 + sl], acc);
  }
  out[(size_t)node * 16 + sl] = acc + sm[SM_CLSC + sl];
}

// g_out = A'(g_in) + cadd  (2 feats, thread per node); FINAL adds sigmoid
template <int FINAL>
__global__ __launch_bounds__(256) void k_agg2(
    const float* __restrict__ gin, const int* __restrict__ rowptr,
    const int* __restrict__ csr_src, const float* __restrict__ csr_w,
    const float* __restrict__ dis, const float* __restrict__ cadd,
    float* __restrict__ gout, int N) {
  int i = blockIdx.x * 256 + threadIdx.x;
  if (i >= N) return;
  const float2* g2 = (const float2*)gin;
  float d = dis[i];
  float2 v = g2[i];
  float a0 = d * d * v.x, a1 = d * d * v.y;
  int e = rowptr[i], end = rowptr[i + 1];
  for (; e < end; ++e) {
    int s = csr_src[e]; float w = csr_w[e];
    float2 u = g2[s];
    a0 = fmaf(w, u.x, a0); a1 = fmaf(w, u.y, a1);
  }
  a0 += cadd[0]; a1 += cadd[1];
  if (FINAL) {
    a0 = 1.f / (1.f + expf(-a0));
    a1 = 1.f / (1.f + expf(-a1));
  }
  ((float2*)gout)[i] = make_float2(a0, a1);
}

extern "C" void kernel_launch(void* const* d_in, const int* in_sizes, int n_in,
                              void* d_out, int out_size, void* d_ws, size_t ws_size,
                              hipStream_t stream) {
  const float* x = (const float*)d_in[0];
  const int* ei = (const int*)d_in[1];   // int32
  const float* W1 = (const float*)d_in[2];
  const float* b1 = (const float*)d_in[3];
  const float* W2 = (const float*)d_in[4];
  const float* b2 = (const float*)d_in[5];
  const float* Wc = (const float*)d_in[6];
  const float* bc = (const float*)d_in[7];
  const float* We1 = (const float*)d_in[8];
  const float* be1 = (const float*)d_in[9];
  const float* We2 = (const float*)d_in[10];
  const float* be2 = (const float*)d_in[11];
  const float* We3 = (const float*)d_in[12];
  const float* be3 = (const float*)d_in[13];
  const float* We4 = (const float*)d_in[14];
  const float* be4 = (const float*)d_in[15];
  const float* Wt = (const float*)d_in[16];
  const float* bt = (const float*)d_in[17];
  float* out = (float*)d_out;

  const int N = in_sizes[0] / 128;
  const int E = in_sizes[1] / 2;

  char* ws = (char*)d_ws;
  size_t off = 0;
  auto alloc = [&](size_t bytes) {
    size_t o = off;
    off = (off + bytes + 255) & ~(size_t)255;
    return o;
  };
  int* deg = (int*)(ws + alloc((size_t)N * 4));
  int* cnt = (int*)(ws + alloc((size_t)N * 4));
  int* rowptr = (int*)(ws + alloc(((size_t)N + 1) * 4));
  float* dis = (float*)(ws + alloc((size_t)N * 4));
  int* csr_src = (int*)(ws + alloc((size_t)E * 4));
  float* csr_w = (float*)(ws + alloc((size_t)E * 4));
  unsigned short* axh = (unsigned short*)(ws + alloc((size_t)N * 128 * 2));
  unsigned short* axl = (unsigned short*)(ws + alloc((size_t)N * 128 * 2));
  float* y16 = (float*)(ws + alloc((size_t)N * 16 * 4));
  float* ga = (float*)(ws + alloc((size_t)N * 2 * 4));
  float* gb = (float*)(ws + alloc((size_t)N * 2 * 4));
  float* sm = (float*)(ws + alloc((size_t)SM_TOTAL * 4));
  unsigned short* w1h = (unsigned short*)(ws + alloc(32768 * 2));
  unsigned short* w1l = (unsigned short*)(ws + alloc(32768 * 2));
  unsigned short* w2h = (unsigned short*)(ws + alloc(4096 * 2));
  unsigned short* w2l = (unsigned short*)(ws + alloc(4096 * 2));

  hipMemsetAsync(deg, 0, (size_t)N * 4, stream);
  hipMemsetAsync(cnt, 0, (size_t)N * 4, stream);

  k_precompute<<<1, 256, 0, stream>>>(W1, W2, b2, Wc, bc, We1, be1, We2, be2,
                                      We3, be3, We4, be4, Wt, bt, sm,
                                      w1h, w1l, w2h, w2l);
  k_deg<<<(E + 255) / 256, 256, 0, stream>>>(ei, deg, E, N);
  k_dis<<<(N + 255) / 256, 256, 0, stream>>>(deg, dis, N);
  k_scan<<<1, 1024, 0, stream>>>(deg, rowptr, N);
  k_scatter<<<(E + 255) / 256, 256, 0, stream>>>(ei, rowptr, cnt, dis, csr_src,
                                                 csr_w, E, N);
  k_agg128<<<(N + 3) / 4, 256, 0, stream>>>(x, rowptr, csr_src, csr_w, dis, sm,
                                            axh, axl, ga, N);
  k_gemm_mfma<<<(N + 63) / 64, 256, 0, stream>>>(axh, axl, w1h, w1l, w2h, w2l,
                                                 b1, y16, N);
  k_agg16<<<(N + 15) / 16, 256, 0, stream>>>(y16, rowptr, csr_src, csr_w, dis,
                                             sm, out, N);
  k_agg2<0><<<(N + 255) / 256, 256, 0, stream>>>(ga, rowptr, csr_src, csr_w,
                                                 dis, sm + SM_C2, gb, N);
  k_agg2<0><<<(N + 255) / 256, 256, 0, stream>>>(gb, rowptr, csr_src, csr_w,
                                                 dis, sm + SM_C3, ga, N);
  k_agg2<1><<<(N + 255) / 256, 256, 0, stream>>>(
      ga, rowptr, csr_src, csr_w, dis, sm + SM_FC, out + (size_t)N * 16, N);
}

// Round 5
// 581.986 us; speedup vs baseline: 1.5125x; 1.2462x over previous
//
#include <hip/hip_runtime.h>
#include <math.h>

// ---------------------------------------------------------------------------
// GCN dual-branch, algebraically restructured:
//   ax = A'x  (128 feats)            [A' = D^-1/2 (A+I) D^-1/2]
//   branch1: y16 = relu(ax@W1 + b1) @ (W2@Wc); cls = A'(y16) + (b2@Wc+bc)
//   branch2 (fully linear): g1 = ax@Me + c1 ; g_{k+1} = A'(g_k) + c_{k+1}
//            trust = sigmoid(A'(g3) + be4@Wt + bt)
// edge_index is INT32 (JAX x64 disabled).
// GEMM runs on MFMA via split-bf16 (hi+lo), ~fp32 accuracy at bf16-MFMA rate.
// ---------------------------------------------------------------------------

#define SM_W2C   0        // 256*16
#define SM_T4    4096     // 128*2
#define SM_T3    4352
#define SM_T2    4608
#define SM_ME    4864
#define SM_CLSC  5120     // 16
#define SM_C1    5136     // 2
#define SM_C2    5138
#define SM_C3    5140
#define SM_FC    5142     // 2  (be4@Wt + bt)
#define SM_TOTAL 5248

typedef __attribute__((ext_vector_type(8))) short bf16x8;
typedef __attribute__((ext_vector_type(4))) float f32x4;
#define MFMA16(a, b, c) __builtin_amdgcn_mfma_f32_16x16x32_bf16(a, b, c, 0, 0, 0)

__device__ inline unsigned short f2bf(float f) {  // RNE f32 -> bf16 bits
  unsigned u = __float_as_uint(f);
  u += 0x7fffu + ((u >> 16) & 1u);
  return (unsigned short)(u >> 16);
}
__device__ inline float bf2f(unsigned short h) {
  return __uint_as_float((unsigned)h << 16);
}

__global__ __launch_bounds__(256) void k_deg(const int* __restrict__ ei,
                                             int* __restrict__ deg, int E, int N) {
  int e = blockIdx.x * 256 + threadIdx.x;
  if (e < E) {
    unsigned c = (unsigned)ei[E + e];
    if (c >= (unsigned)N) c = 0;
    atomicAdd(&deg[c], 1);
  }
}

// phase 1: per-block inclusive scan of deg -> rowptr[i+1] (pre-offset),
// block totals -> bsum; fused dis = rsqrt(deg+1).
__global__ __launch_bounds__(1024) void k_scan1(const int* __restrict__ deg,
                                                int* __restrict__ rowptr,
                                                int* __restrict__ bsum,
                                                float* __restrict__ dis, int n) {
  __shared__ int wsum[16];
  int tid = threadIdx.x, lane = tid & 63, wid = tid >> 6;
  int i = blockIdx.x * 1024 + tid;
  int v = (i < n) ? deg[i] : 0;
  if (i < n) dis[i] = 1.0f / sqrtf((float)v + 1.0f);
  int x = v;
  #pragma unroll
  for (int off = 1; off < 64; off <<= 1) {
    int t = __shfl_up(x, off, 64);
    if (lane >= off) x += t;
  }
  if (lane == 63) wsum[wid] = x;
  __syncthreads();
  if (wid == 0 && lane < 16) {
    int ws = wsum[lane];
    #pragma unroll
    for (int off = 1; off < 16; off <<= 1) {
      int t = __shfl_up(ws, off, 64);
      if (lane >= off) ws += t;
    }
    wsum[lane] = ws;
  }
  __syncthreads();
  int incl = x + (wid ? wsum[wid - 1] : 0);
  if (i < n) rowptr[i + 1] = incl;
  if (tid == 0) bsum[blockIdx.x] = wsum[15];
}

// phase 2: exclusive scan of the (<=128) block totals, in place
__global__ __launch_bounds__(128) void k_scan2(int* __restrict__ bsum,
                                               int* __restrict__ rowptr, int B) {
  __shared__ int s[128];
  int tid = threadIdx.x;
  s[tid] = (tid < B) ? bsum[tid] : 0;
  __syncthreads();
  if (tid == 0) {
    int acc = 0;
    for (int j = 0; j < B; ++j) { int t = s[j]; s[j] = acc; acc += t; }
    rowptr[0] = 0;
  }
  __syncthreads();
  if (tid < B) bsum[tid] = s[tid];
}

// phase 3: add block offsets
__global__ __launch_bounds__(256) void k_scan3(int* __restrict__ rowptr,
                                               const int* __restrict__ bsum, int n) {
  int i = blockIdx.x * 256 + threadIdx.x;
  if (i < n) rowptr[i + 1] += bsum[i >> 10];
}

__global__ __launch_bounds__(256) void k_scatter(const int* __restrict__ ei,
                                                 const int* __restrict__ rowptr,
                                                 int* __restrict__ cnt,
                                                 const float* __restrict__ dis,
                                                 int* __restrict__ csr_src,
                                                 float* __restrict__ csr_w,
                                                 int E, int N) {
  int e = blockIdx.x * 256 + threadIdx.x;
  if (e >= E) return;
  unsigned r = (unsigned)ei[e];
  unsigned c = (unsigned)ei[E + e];
  if (r >= (unsigned)N) r = 0;
  if (c >= (unsigned)N) c = 0;
  int pos = rowptr[c] + atomicAdd(&cnt[c], 1);
  csr_src[pos] = (int)r;
  csr_w[pos] = dis[r] * dis[c];
}

// fold weight chains + bf16 hi/lo splits. Grid = 33 blocks:
//   b in [0,16): W2C rows 16b..16b+16 (compute + split, same thread)
//   b in [16,32): W1 split chunk of 2048 elems
//   b == 32: serial 2-wide chains + CLSC + C1..C3 + FC
__global__ __launch_bounds__(256) void k_precompute(
    const float* __restrict__ W1,
    const float* __restrict__ W2, const float* __restrict__ b2,
    const float* __restrict__ Wc, const float* __restrict__ bc,
    const float* __restrict__ We1, const float* __restrict__ be1,
    const float* __restrict__ We2, const float* __restrict__ be2,
    const float* __restrict__ We3, const float* __restrict__ be3,
    const float* __restrict__ We4, const float* __restrict__ be4,
    const float* __restrict__ Wt, const float* __restrict__ bt,
    float* __restrict__ sm,
    unsigned short* __restrict__ w1h, unsigned short* __restrict__ w1l,
    unsigned short* __restrict__ w2h, unsigned short* __restrict__ w2l) {
  int tid = threadIdx.x, b = blockIdx.x;
  if (b < 16) {
    int r = b * 16 + (tid >> 4), c = tid & 15;
    float s = 0.f;
    #pragma unroll 4
    for (int k = 0; k < 128; ++k) s += W2[(size_t)r * 128 + k] * Wc[k * 16 + c];
    sm[SM_W2C + r * 16 + c] = s;
    unsigned short h = f2bf(s);
    w2h[c * 256 + r] = h;                 // w2t[c][k=r]
    w2l[c * 256 + r] = f2bf(s - bf2f(h));
    return;
  }
  if (b < 32) {
    int base = (b - 16) * 2048;
    #pragma unroll
    for (int it = 0; it < 8; ++it) {
      int idx = base + it * 256 + tid;    // w1t[c][k]
      int c = idx >> 7, k = idx & 127;
      float v = W1[(size_t)k * 256 + c];
      unsigned short h = f2bf(v);
      w1h[idx] = h;
      w1l[idx] = f2bf(v - bf2f(h));
    }
    return;
  }
  // b == 32: chains
  {
    int r = tid >> 1, c = tid & 1; float s = 0.f;
    for (int k = 0; k < 128; ++k) s += We4[r * 128 + k] * Wt[k * 2 + c];
    sm[SM_T4 + r * 2 + c] = s;
  }
  __syncthreads();
  {
    int r = tid >> 1, c = tid & 1; float s = 0.f;
    for (int k = 0; k < 128; ++k) s += We3[r * 128 + k] * sm[SM_T4 + k * 2 + c];
    sm[SM_T3 + r * 2 + c] = s;
  }
  __syncthreads();
  {
    int r = tid >> 1, c = tid & 1; float s = 0.f;
    for (int k = 0; k < 128; ++k) s += We2[r * 128 + k] * sm[SM_T3 + k * 2 + c];
    sm[SM_T2 + r * 2 + c] = s;
  }
  __syncthreads();
  {
    int r = tid >> 1, c = tid & 1; float s = 0.f;
    for (int k = 0; k < 128; ++k) s += We1[r * 128 + k] * sm[SM_T2 + k * 2 + c];
    sm[SM_ME + r * 2 + c] = s;
  }
  if (tid < 16) {
    float s = 0.f;
    for (int k = 0; k < 128; ++k) s += b2[k] * Wc[k * 16 + tid];
    sm[SM_CLSC + tid] = s + bc[tid];
  }
  __syncthreads();
  if (tid < 2) {
    float s = 0.f;
    for (int k = 0; k < 128; ++k) s += be1[k] * sm[SM_T2 + k * 2 + tid];
    sm[SM_C1 + tid] = s;
    s = 0.f;
    for (int k = 0; k < 128; ++k) s += be2[k] * sm[SM_T3 + k * 2 + tid];
    sm[SM_C2 + tid] = s;
    s = 0.f;
    for (int k = 0; k < 128; ++k) s += be3[k] * sm[SM_T4 + k * 2 + tid];
    sm[SM_C3 + tid] = s;
    s = 0.f;
    for (int k = 0; k < 128; ++k) s += be4[k] * Wt[k * 2 + tid];
    sm[SM_FC + tid] = s + bt[tid];
  }
}

// ax = A'x (wave per node), written as bf16 hi/lo split; fused g1 = ax@Me + c1
__global__ __launch_bounds__(256) void k_agg128(
    const float* __restrict__ x, const int* __restrict__ rowptr,
    const int* __restrict__ csr_src, const float* __restrict__ csr_w,
    const float* __restrict__ dis, const float* __restrict__ sm,
    unsigned short* __restrict__ axh, unsigned short* __restrict__ axl,
    float* __restrict__ ga, int N) {
  int node = blockIdx.x * 4 + (threadIdx.x >> 6);
  if (node >= N) return;
  int lane = threadIdx.x & 63;
  const float2* x2 = (const float2*)x;
  float d = dis[node];
  float2 v = x2[(size_t)node * 64 + lane];
  float a0 = d * d * v.x, a1 = d * d * v.y;
  int e = rowptr[node], end = rowptr[node + 1];
  while (e < end) {
    int rem = end - e;
    int cnt = rem < 64 ? rem : 64;
    int off = lane < cnt ? lane : cnt - 1;
    int src_l = csr_src[e + off];
    int w_l = __float_as_int(csr_w[e + off]);
    for (int i = 0; i < cnt; ++i) {
      int s = __builtin_amdgcn_readlane(src_l, i);
      float w = __int_as_float(__builtin_amdgcn_readlane(w_l, i));
      float2 u = x2[(size_t)s * 64 + lane];
      a0 = fmaf(w, u.x, a0);
      a1 = fmaf(w, u.y, a1);
    }
    e += 64;
  }
  unsigned short h0 = f2bf(a0), h1v = f2bf(a1);
  unsigned short l0 = f2bf(a0 - bf2f(h0)), l1 = f2bf(a1 - bf2f(h1v));
  ((unsigned int*)axh)[(size_t)node * 64 + lane] = (unsigned)h0 | ((unsigned)h1v << 16);
  ((unsigned int*)axl)[(size_t)node * 64 + lane] = (unsigned)l0 | ((unsigned)l1 << 16);
  float4 me = *(const float4*)&sm[SM_ME + lane * 4];
  float p0 = a0 * me.x + a1 * me.z;
  float p1 = a0 * me.y + a1 * me.w;
  #pragma unroll
  for (int m = 32; m; m >>= 1) { p0 += __shfl_xor(p0, m); p1 += __shfl_xor(p1, m); }
  if (lane == 0)
    ((float2*)ga)[node] = make_float2(p0 + sm[SM_C1 + 0], p1 + sm[SM_C1 + 1]);
}

// y16 = relu(ax@W1 + b1) @ W2c via split-bf16 MFMA (layouts verified in R4).
__global__ __launch_bounds__(256, 2) void k_gemm_mfma(
    const unsigned short* __restrict__ axh, const unsigned short* __restrict__ axl,
    const unsigned short* __restrict__ w1h, const unsigned short* __restrict__ w1l,
    const unsigned short* __restrict__ w2h, const unsigned short* __restrict__ w2l,
    const float* __restrict__ b1, float* __restrict__ Y, int N) {
  __shared__ unsigned short lds[32768];  // 64 KB
  int tid = threadIdx.x, lane = tid & 63, w = tid >> 6;
  int r16 = lane & 15, kh = lane >> 4;
  int m0 = blockIdx.x * 64;
  #pragma unroll
  for (int it = 0; it < 8; ++it) {
    int idx = it * 256 + tid;            // 0..2047 chunks of 16B
    int arr = idx >> 10, rem = idx & 1023;
    int row = rem >> 4, ch = rem & 15;
    int gr = m0 + row; if (gr > N - 1) gr = N - 1;
    const unsigned short* src = (arr ? axl : axh) + (size_t)gr * 128 + ch * 8;
    uint4 vv = *(const uint4*)src;
    *(uint4*)&lds[arr * 8192 + row * 128 + ((ch ^ (row & 7)) * 8)] = vv;
  }
  __syncthreads();
  f32x4 acc[4][4];
  #pragma unroll
  for (int i = 0; i < 4; ++i)
    #pragma unroll
    for (int j = 0; j < 4; ++j) acc[i][j] = (f32x4){0.f, 0.f, 0.f, 0.f};
  #pragma unroll
  for (int ks = 0; ks < 4; ++ks) {
    bf16x8 bh[4], bl[4];
    #pragma unroll
    for (int nt = 0; nt < 4; ++nt) {
      int col = w * 64 + nt * 16 + r16;
      size_t boff = (size_t)col * 128 + ks * 32 + kh * 8;
      bh[nt] = *(const bf16x8*)(w1h + boff);
      bl[nt] = *(const bf16x8*)(w1l + boff);
    }
    #pragma unroll
    for (int mt = 0; mt < 4; ++mt) {
      int row = mt * 16 + r16;
      int ch = ks * 4 + kh;
      int off = row * 128 + ((ch ^ (row & 7)) * 8);
      bf16x8 ah = *(const bf16x8*)&lds[off];
      bf16x8 al = *(const bf16x8*)&lds[8192 + off];
      #pragma unroll
      for (int nt = 0; nt < 4; ++nt) {
        acc[mt][nt] = MFMA16(ah, bh[nt], acc[mt][nt]);
        acc[mt][nt] = MFMA16(ah, bl[nt], acc[mt][nt]);
        acc[mt][nt] = MFMA16(al, bh[nt], acc[mt][nt]);
      }
    }
  }
  __syncthreads();
  #pragma unroll
  for (int nt = 0; nt < 4; ++nt) {
    int colL = w * 64 + nt * 16 + r16;
    float bv = b1[colL];
    #pragma unroll
    for (int mt = 0; mt < 4; ++mt) {
      #pragma unroll
      for (int r = 0; r < 4; ++r) {
        int rowL = mt * 16 + kh * 4 + r;
        float vv = acc[mt][nt][r] + bv;
        vv = vv > 0.f ? vv : 0.f;
        unsigned short hh = f2bf(vv);
        unsigned short ll = f2bf(vv - bf2f(hh));
        int idx = rowL * 256 + (colL ^ ((rowL & 7) << 3));
        lds[idx] = hh;
        lds[16384 + idx] = ll;
      }
    }
  }
  __syncthreads();
  f32x4 y = (f32x4){0.f, 0.f, 0.f, 0.f};
  int rowL = w * 16 + r16;
  #pragma unroll
  for (int k2 = 0; k2 < 8; ++k2) {
    int cb = k2 * 32 + kh * 8;
    int idx = rowL * 256 + (cb ^ ((rowL & 7) << 3));
    bf16x8 a2h = *(const bf16x8*)&lds[idx];
    bf16x8 a2l = *(const bf16x8*)&lds[16384 + idx];
    size_t boff = (size_t)r16 * 256 + cb;
    bf16x8 b2h = *(const bf16x8*)(w2h + boff);
    bf16x8 b2l = *(const bf16x8*)(w2l + boff);
    y = MFMA16(a2h, b2h, y);
    y = MFMA16(a2h, b2l, y);
    y = MFMA16(a2l, b2h, y);
  }
  #pragma unroll
  for (int r = 0; r < 4; ++r) {
    int gr = m0 + w * 16 + kh * 4 + r;
    if (gr < N) Y[(size_t)gr * 16 + r16] = y[r];
  }
}

// cls = A'(y16) + cls_const  (16 lanes per node) -> d_out
__global__ __launch_bounds__(256) void k_agg16(
    const float* __restrict__ Y, const int* __restrict__ rowptr,
    const int* __restrict__ csr_src, const float* __restrict__ csr_w,
    const float* __restrict__ dis, const float* __restrict__ sm,
    float* __restrict__ out, int N) {
  int node = blockIdx.x * 16 + (threadIdx.x >> 4);
  if (node >= N) return;
  int sl = threadIdx.x & 15;
  float d = dis[node];
  float acc = d * d * Y[(size_t)node * 16 + sl];
  int e = rowptr[node], end = rowptr[node + 1];
  for (; e < end; ++e) {
    int s = csr_src[e]; float w = csr_w[e];
    acc = fmaf(w, Y[(size_t)s * 16 + sl], acc);
  }
  out[(size_t)node * 16 + sl] = acc + sm[SM_CLSC + sl];
}

// g_out = A'(g_in) + cadd  (2 feats, thread per node); FINAL adds sigmoid
template <int FINAL>
__global__ __launch_bounds__(256) void k_agg2(
    const float* __restrict__ gin, const int* __restrict__ rowptr,
    const int* __restrict__ csr_src, const float* __restrict__ csr_w,
    const float* __restrict__ dis, const float* __restrict__ cadd,
    float* __restrict__ gout, int N) {
  int i = blockIdx.x * 256 + threadIdx.x;
  if (i >= N) return;
  const float2* g2 = (const float2*)gin;
  float d = dis[i];
  float2 v = g2[i];
  float a0 = d * d * v.x, a1 = d * d * v.y;
  int e = rowptr[i], end = rowptr[i + 1];
  for (; e < end; ++e) {
    int s = csr_src[e]; float w = csr_w[e];
    float2 u = g2[s];
    a0 = fmaf(w, u.x, a0); a1 = fmaf(w, u.y, a1);
  }
  a0 += cadd[0]; a1 += cadd[1];
  if (FINAL) {
    a0 = 1.f / (1.f + expf(-a0));
    a1 = 1.f / (1.f + expf(-a1));
  }
  ((float2*)gout)[i] = make_float2(a0, a1);
}

extern "C" void kernel_launch(void* const* d_in, const int* in_sizes, int n_in,
                              void* d_out, int out_size, void* d_ws, size_t ws_size,
                              hipStream_t stream) {
  const float* x = (const float*)d_in[0];
  const int* ei = (const int*)d_in[1];   // int32
  const float* W1 = (const float*)d_in[2];
  const float* b1 = (const float*)d_in[3];
  const float* W2 = (const float*)d_in[4];
  const float* b2 = (const float*)d_in[5];
  const float* Wc = (const float*)d_in[6];
  const float* bc = (const float*)d_in[7];
  const float* We1 = (const float*)d_in[8];
  const float* be1 = (const float*)d_in[9];
  const float* We2 = (const float*)d_in[10];
  const float* be2 = (const float*)d_in[11];
  const float* We3 = (const float*)d_in[12];
  const float* be3 = (const float*)d_in[13];
  const float* We4 = (const float*)d_in[14];
  const float* be4 = (const float*)d_in[15];
  const float* Wt = (const float*)d_in[16];
  const float* bt = (const float*)d_in[17];
  float* out = (float*)d_out;

  const int N = in_sizes[0] / 128;
  const int E = in_sizes[1] / 2;
  const int NB = (N + 1023) / 1024;      // scan blocks (<=128)

  char* ws = (char*)d_ws;
  size_t off = 0;
  auto alloc = [&](size_t bytes) {
    size_t o = off;
    off = (off + bytes + 255) & ~(size_t)255;
    return o;
  };
  int* deg = (int*)(ws + alloc((size_t)N * 8));   // deg + cnt adjacent
  int* cnt = deg + N;
  int* rowptr = (int*)(ws + alloc(((size_t)N + 1) * 4));
  int* bsum = (int*)(ws + alloc(128 * 4));
  float* dis = (float*)(ws + alloc((size_t)N * 4));
  int* csr_src = (int*)(ws + alloc((size_t)E * 4));
  float* csr_w = (float*)(ws + alloc((size_t)E * 4));
  unsigned short* axh = (unsigned short*)(ws + alloc((size_t)N * 128 * 2));
  unsigned short* axl = (unsigned short*)(ws + alloc((size_t)N * 128 * 2));
  float* y16 = (float*)(ws + alloc((size_t)N * 16 * 4));
  float* ga = (float*)(ws + alloc((size_t)N * 2 * 4));
  float* gb = (float*)(ws + alloc((size_t)N * 2 * 4));
  float* sm = (float*)(ws + alloc((size_t)SM_TOTAL * 4));
  unsigned short* w1h = (unsigned short*)(ws + alloc(32768 * 2));
  unsigned short* w1l = (unsigned short*)(ws + alloc(32768 * 2));
  unsigned short* w2h = (unsigned short*)(ws + alloc(4096 * 2));
  unsigned short* w2l = (unsigned short*)(ws + alloc(4096 * 2));

  hipMemsetAsync(deg, 0, (size_t)N * 8, stream);

  k_precompute<<<33, 256, 0, stream>>>(W1, W2, b2, Wc, bc, We1, be1, We2, be2,
                                       We3, be3, We4, be4, Wt, bt, sm,
                                       w1h, w1l, w2h, w2l);
  k_deg<<<(E + 255) / 256, 256, 0, stream>>>(ei, deg, E, N);
  k_scan1<<<NB, 1024, 0, stream>>>(deg, rowptr, bsum, dis, N);
  k_scan2<<<1, 128, 0, stream>>>(bsum, rowptr, NB);
  k_scan3<<<(N + 255) / 256, 256, 0, stream>>>(rowptr, bsum, N);
  k_scatter<<<(E + 255) / 256, 256, 0, stream>>>(ei, rowptr, cnt, dis, csr_src,
                                                 csr_w, E, N);
  k_agg128<<<(N + 3) / 4, 256, 0, stream>>>(x, rowptr, csr_src, csr_w, dis, sm,
                                            axh, axl, ga, N);
  k_gemm_mfma<<<(N + 63) / 64, 256, 0, stream>>>(axh, axl, w1h, w1l, w2h, w2l,
                                                 b1, y16, N);
  k_agg16<<<(N + 15) / 16, 256, 0, stream>>>(y16, rowptr, csr_src, csr_w, dis,
                                             sm, out, N);
  k_agg2<0><<<(N + 255) / 256, 256, 0, stream>>>(ga, rowptr, csr_src, csr_w,
                                                 dis, sm + SM_C2, gb, N);
  k_agg2<0><<<(N + 255) / 256, 256, 0, stream>>>(gb, rowptr, csr_src, csr_w,
                                                 dis, sm + SM_C3, ga, N);
  k_agg2<1><<<(N + 255) / 256, 256, 0, stream>>>(
      ga, rowptr, csr_src, csr_w, dis, sm + SM_FC, out + (size_t)N * 16, N);
}